// Round 2
// baseline (4300.914 us; speedup 1.0000x reference)
//
#include <hip/hip_runtime.h>

typedef _Float16 f16x8 __attribute__((ext_vector_type(8)));
typedef float    f32x4 __attribute__((ext_vector_type(4)));

#define NTRAJ  4096
#define LSTEPS 128
#define IDIM   32
#define LD     64
#define NU     256

// frag bases (units of 1KB frags) in d_ws; lo-set lives at +NFRAGS
#define FB_WO1 0
#define FB_WO2 32
#define FB_WU1 64
#define FB_WU2 144
#define FB_WR1 176
#define FB_WR2 256
#define FB_WN1 288
#define FB_WN2 368
#define NFRAGS 432

// LDS pitches (elements)
#define PF  68    // fp32 width-64 arrays
#define PBY 72    // f16 width-64 arrays
#define PBX 40    // f16 width-32
#define PBC 136   // f16 width-128
#define PBH 520   // f16 width-512

static __device__ __forceinline__ float sigmoid_fast(float x) {
  float t = __builtin_amdgcn_exp2f(x * -1.442695041f);
  return __builtin_amdgcn_rcpf(1.0f + t);
}
static __device__ __forceinline__ float tanh_fast(float x) {
  float t = __builtin_amdgcn_exp2f(x * -2.885390082f);
  return __builtin_amdgcn_rcpf(1.0f + t) * 2.0f - 1.0f;
}

// triple-product split-fp16 MFMA: A*B with ~22-bit mantissa fidelity
static __device__ __forceinline__ f32x4 mm3(f16x8 ah, f16x8 al, f16x8 bh, f16x8 bl, f32x4 c) {
  c = __builtin_amdgcn_mfma_f32_16x16x32_f16(ah, bh, c, 0, 0, 0);
  c = __builtin_amdgcn_mfma_f32_16x16x32_f16(al, bh, c, 0, 0, 0);
  c = __builtin_amdgcn_mfma_f32_16x16x32_f16(ah, bl, c, 0, 0, 0);
  return c;
}

// ---------------- weight prep: fp32 [K][N] -> f16 hi/lo B-fragment swizzle ----------------
__global__ void prep_weights(const float* __restrict__ Wo1, const float* __restrict__ Wo2,
                             const float* __restrict__ Wu1, const float* __restrict__ Wu2,
                             const float* __restrict__ Wr1, const float* __restrict__ Wr2,
                             const float* __restrict__ Wn1, const float* __restrict__ Wn2,
                             f16x8* __restrict__ ws)
{
  int f = blockIdx.x;
  const float* W; int N; int base;
  if (f < 32)       { W = Wo1; N = 256; base = 0;   }
  else if (f < 64)  { W = Wo2; N = 64;  base = 32;  }
  else if (f < 144) { W = Wu1; N = 256; base = 64;  }
  else if (f < 176) { W = Wu2; N = 64;  base = 144; }
  else if (f < 256) { W = Wr1; N = 256; base = 176; }
  else if (f < 288) { W = Wr2; N = 64;  base = 256; }
  else if (f < 368) { W = Wn1; N = 256; base = 288; }
  else              { W = Wn2; N = 128; base = 368; }
  int fl  = f - base;
  int nts = N >> 4;
  int kc  = fl / nts;
  int nt  = fl - kc * nts;
  int l   = threadIdx.x;
  int k0  = kc * 32 + (l >> 4) * 8;
  int n   = nt * 16 + (l & 15);
  f16x8 h, lo;
#pragma unroll
  for (int j = 0; j < 8; ++j) {
    float w = W[(size_t)(k0 + j) * N + n];
    _Float16 hh = (_Float16)w;
    h[j]  = hh;
    lo[j] = (_Float16)(w - (float)hh);
  }
  ws[f * 64 + l]            = h;
  ws[(NFRAGS + f) * 64 + l] = lo;
}

// ---------------- main persistent-scan kernel ----------------
__global__ __launch_bounds__(512) void vae_main(
    const float* __restrict__ data, const float* __restrict__ ts,
    const float* __restrict__ bo1, const float* __restrict__ bo2,
    const float* __restrict__ bu1, const float* __restrict__ bu2,
    const float* __restrict__ br1, const float* __restrict__ br2,
    const float* __restrict__ bn1, const float* __restrict__ bn2,
    const f16x8* __restrict__ WF, float* __restrict__ out)
{
  __shared__ float s_y[16*PF], s_lv[16*PF], s_yode[16*PF], s_U[16*PF], s_R[16*PF];
  __shared__ float s_bias[1344];
  __shared__ float s_dts[LSTEPS];
  __shared__ __align__(16) _Float16 b_y[2][16*PBY], b_lv[2][16*PBY], b_yode[2][16*PBY];
  __shared__ __align__(16) _Float16 b_x[2][16*PBX], b_cc[2][16*PBC], b_hid[2][16*PBH];

  const int tid  = threadIdx.x;
  const int lane = tid & 63;
  const int wave = tid >> 6;
  const int q    = lane >> 4;
  const int l16  = lane & 15;
  const int q8   = q * 8;
  const int traj0 = blockIdx.x * 16;

#define BH(base, nts, kc, nt) WF[((base) + (kc)*(nts) + (nt)) * 64 + lane]
#define BL(base, nts, kc, nt) WF[(NFRAGS + (base) + (kc)*(nts) + (nt)) * 64 + lane]
#define LDA(arr, pitch, koff) (*(const f16x8*)&(arr)[(l16)*(pitch) + (koff) + q8])
#define STB(arr, pitch, row, col, v) do {                            \
    float _v = (v); _Float16 _h = (_Float16)_v;                      \
    arr[0][(row)*(pitch)+(col)] = _h;                                \
    arr[1][(row)*(pitch)+(col)] = (_Float16)(_v - (float)_h);        \
  } while (0)

  // stage biases / dts, zero state
  for (int i = tid; i < NU; i += 512) s_bias[0    + i] = bo1[i];
  if (tid < LD)                       s_bias[256  + tid] = bo2[tid];
  for (int i = tid; i < NU; i += 512) s_bias[320  + i] = bu1[i];
  if (tid < LD)                       s_bias[576  + tid] = bu2[tid];
  for (int i = tid; i < NU; i += 512) s_bias[640  + i] = br1[i];
  if (tid < LD)                       s_bias[896  + tid] = br2[tid];
  for (int i = tid; i < NU; i += 512) s_bias[960  + i] = bn1[i];
  if (tid < 2*LD)                     s_bias[1216 + tid] = bn2[tid];
  if (tid < LSTEPS-1) s_dts[tid] = (tid == 0) ? (ts[1] - ts[0]) : (ts[tid] - ts[tid+1]);
  for (int i = tid; i < 16*PF;  i += 512) { s_y[i] = 0.f; s_lv[i] = 0.f; }
  for (int i = tid; i < 2*16*PBY; i += 512) {
    ((_Float16*)b_y)[i]  = (_Float16)0.f;
    ((_Float16*)b_lv)[i] = (_Float16)0.f;
  }
  __syncthreads();

  for (int t = 0; t < LSTEPS-1; ++t) {
    // load x(t) = data[:, t+1, :]  (16 x 32), split hi/lo
    {
      int row = tid >> 5, c = tid & 31;
      float v = data[(size_t)(traj0 + row) * LSTEPS * IDIM + (size_t)(t+1) * IDIM + c];
      STB(b_x, PBX, row, c, v);
    }
    float dt = s_dts[t];
    __syncthreads();

    // ---- S1: hid_o = tanh(y @ Wo1 + bo1)  [16x256] ----
    {
      f16x8 a0h = LDA(b_y[0], PBY, 0),  a0l = LDA(b_y[1], PBY, 0);
      f16x8 a1h = LDA(b_y[0], PBY, 32), a1l = LDA(b_y[1], PBY, 32);
      int nt0 = wave * 2;
      f32x4 acc[2];
      acc[0] = (f32x4){0.f,0.f,0.f,0.f};
      acc[1] = (f32x4){0.f,0.f,0.f,0.f};
#pragma unroll
      for (int s = 0; s < 2; ++s) {
        acc[s] = mm3(a0h, a0l, BH(FB_WO1,16,0,nt0+s), BL(FB_WO1,16,0,nt0+s), acc[s]);
        acc[s] = mm3(a1h, a1l, BH(FB_WO1,16,1,nt0+s), BL(FB_WO1,16,1,nt0+s), acc[s]);
      }
#pragma unroll
      for (int s = 0; s < 2; ++s) {
        int col = (nt0 + s) * 16 + l16;
        float bb = s_bias[0 + col];
#pragma unroll
        for (int r = 0; r < 4; ++r) {
          int row = q*4 + r;
          STB(b_hid, PBH, row, col, tanh_fast(acc[s][r] + bb));
        }
      }
    }
    __syncthreads();

    // ---- S2: yode = y + dt*(hid_o @ Wo2 + bo2)  [16x64], waves 0-3 ----
    if (wave < 4) {
      f32x4 acc = {0.f,0.f,0.f,0.f};
#pragma unroll
      for (int kc = 0; kc < 8; ++kc) {
        f16x8 ah = LDA(b_hid[0], PBH, kc*32), al = LDA(b_hid[1], PBH, kc*32);
        acc = mm3(ah, al, BH(FB_WO2,4,kc,wave), BL(FB_WO2,4,kc,wave), acc);
      }
      int col = wave * 16 + l16;
      float bb = s_bias[256 + col];
#pragma unroll
      for (int r = 0; r < 4; ++r) {
        int row = q*4 + r;
        float yo = s_y[row*PF + col] + dt * (acc[r] + bb);
        s_yode[row*PF + col] = yo;
        STB(b_yode, PBY, row, col, yo);
      }
    }
    __syncthreads();

    // ---- S3: hid_ur = tanh(yc @ [Wu1|Wr1] + b)  [16x512] ----
    {
      f16x8 ah[5], al[5];
      ah[0] = LDA(b_yode[0], PBY, 0);  al[0] = LDA(b_yode[1], PBY, 0);
      ah[1] = LDA(b_yode[0], PBY, 32); al[1] = LDA(b_yode[1], PBY, 32);
      ah[2] = LDA(b_lv[0],   PBY, 0);  al[2] = LDA(b_lv[1],   PBY, 0);
      ah[3] = LDA(b_lv[0],   PBY, 32); al[3] = LDA(b_lv[1],   PBY, 32);
      ah[4] = LDA(b_x[0],    PBX, 0);  al[4] = LDA(b_x[1],    PBX, 0);
      int isR  = wave >> 2;
      int fb   = isR ? FB_WR1 : FB_WU1;
      int nt0  = (wave & 3) * 4;
      int bofs = isR ? 640 : 320;
      int cofs = isR ? 256 : 0;
      f32x4 acc[4];
#pragma unroll
      for (int s = 0; s < 4; ++s) acc[s] = (f32x4){0.f,0.f,0.f,0.f};
#pragma unroll
      for (int kc = 0; kc < 5; ++kc)
#pragma unroll
        for (int s = 0; s < 4; ++s)
          acc[s] = mm3(ah[kc], al[kc], BH(fb,16,kc,nt0+s), BL(fb,16,kc,nt0+s), acc[s]);
#pragma unroll
      for (int s = 0; s < 4; ++s) {
        int col = (nt0 + s) * 16 + l16;
        float bb = s_bias[bofs + col];
#pragma unroll
        for (int r = 0; r < 4; ++r) {
          int row = q*4 + r;
          STB(b_hid, PBH, row, cofs + col, tanh_fast(acc[s][r] + bb));
        }
      }
    }
    __syncthreads();

    // ---- S4: U = sig(hid_u @ Wu2 + bu2), R = sig(hid_r @ Wr2 + br2)  [16x64 each] ----
    {
      int isR  = wave >> 2;
      int fb   = isR ? FB_WR2 : FB_WU2;
      int nt   = wave & 3;
      int aofs = isR ? 256 : 0;
      int bofs = isR ? 896 : 576;
      float* dst = isR ? s_R : s_U;
      f32x4 acc = {0.f,0.f,0.f,0.f};
#pragma unroll
      for (int kc = 0; kc < 8; ++kc) {
        f16x8 ah = LDA(b_hid[0], PBH, aofs + kc*32), al = LDA(b_hid[1], PBH, aofs + kc*32);
        acc = mm3(ah, al, BH(fb,4,kc,nt), BL(fb,4,kc,nt), acc);
      }
      int col = nt * 16 + l16;
      float bb = s_bias[bofs + col];
#pragma unroll
      for (int r = 0; r < 4; ++r)
        dst[(q*4 + r)*PF + col] = sigmoid_fast(acc[r] + bb);
    }
    __syncthreads();

    // ---- cc build: [yode*R | lv*R] -> f16 hi/lo ----
    {
#pragma unroll
      for (int i = 0; i < 4; ++i) {
        int e = tid + i * 512;
        int row = e >> 7, c = e & 127;
        float src = (c < 64) ? s_yode[row*PF + c] : s_lv[row*PF + (c - 64)];
        float v = src * s_R[row*PF + (c & 63)];
        STB(b_cc, PBC, row, c, v);
      }
    }
    __syncthreads();

    // ---- S5: hid_n = tanh(cc @ Wn1 + bn1)  [16x256] ----
    {
      f16x8 ah[5], al[5];
      ah[0] = LDA(b_cc[0], PBC, 0);  al[0] = LDA(b_cc[1], PBC, 0);
      ah[1] = LDA(b_cc[0], PBC, 32); al[1] = LDA(b_cc[1], PBC, 32);
      ah[2] = LDA(b_cc[0], PBC, 64); al[2] = LDA(b_cc[1], PBC, 64);
      ah[3] = LDA(b_cc[0], PBC, 96); al[3] = LDA(b_cc[1], PBC, 96);
      ah[4] = LDA(b_x[0],  PBX, 0);  al[4] = LDA(b_x[1],  PBX, 0);
      int nt0 = wave * 2;
      f32x4 acc[2];
      acc[0] = (f32x4){0.f,0.f,0.f,0.f};
      acc[1] = (f32x4){0.f,0.f,0.f,0.f};
#pragma unroll
      for (int kc = 0; kc < 5; ++kc)
#pragma unroll
        for (int s = 0; s < 2; ++s)
          acc[s] = mm3(ah[kc], al[kc], BH(FB_WN1,16,kc,nt0+s), BL(FB_WN1,16,kc,nt0+s), acc[s]);
#pragma unroll
      for (int s = 0; s < 2; ++s) {
        int col = (nt0 + s) * 16 + l16;
        float bb = s_bias[960 + col];
#pragma unroll
        for (int r = 0; r < 4; ++r) {
          int row = q*4 + r;
          STB(b_hid, PBH, row, col, tanh_fast(acc[s][r] + bb));
        }
      }
    }
    __syncthreads();

    // ---- S6: h = hid_n @ Wn2 + bn2  [16x128]; GRU gating, state update ----
    {
      f32x4 acc = {0.f,0.f,0.f,0.f};
#pragma unroll
      for (int kc = 0; kc < 8; ++kc) {
        f16x8 ah = LDA(b_hid[0], PBH, kc*32), al = LDA(b_hid[1], PBH, kc*32);
        acc = mm3(ah, al, BH(FB_WN2,8,kc,wave), BL(FB_WN2,8,kc,wave), acc);
      }
      int col = wave * 16 + l16;
      float bb = s_bias[1216 + col];
      if (col < LD) {
#pragma unroll
        for (int r = 0; r < 4; ++r) {
          int row = q*4 + r;
          float h = acc[r] + bb;
          float u = s_U[row*PF + col];
          float nv = (1.f - u) * h + u * s_yode[row*PF + col];
          s_y[row*PF + col] = nv;
          STB(b_y, PBY, row, col, nv);
        }
      } else {
        int c2 = col - LD;
#pragma unroll
        for (int r = 0; r < 4; ++r) {
          int row = q*4 + r;
          float h = fabsf(acc[r] + bb);
          float u = s_U[row*PF + c2];
          float nl = (1.f - u) * h + u * s_lv[row*PF + c2];
          s_lv[row*PF + c2] = nl;
          STB(b_lv, PBY, row, c2, nl);
        }
      }
    }
    __syncthreads();
  }

  // write outputs: (yi, yi_logvar) concatenated
  for (int i = tid; i < 1024; i += 512) {
    int row = i >> 6, c = i & 63;
    out[(size_t)(traj0 + row) * LD + c] = s_y[row*PF + c];
    out[(size_t)NTRAJ * LD + (size_t)(traj0 + row) * LD + c] = s_lv[row*PF + c];
  }
}

extern "C" void kernel_launch(void* const* d_in, const int* in_sizes, int n_in,
                              void* d_out, int out_size, void* d_ws, size_t ws_size,
                              hipStream_t stream) {
  const float* data = (const float*)d_in[0];
  const float* ts   = (const float*)d_in[1];
  const float* Wo1  = (const float*)d_in[2];  const float* bo1 = (const float*)d_in[3];
  const float* Wo2  = (const float*)d_in[4];  const float* bo2 = (const float*)d_in[5];
  const float* Wu1  = (const float*)d_in[6];  const float* bu1 = (const float*)d_in[7];
  const float* Wr1  = (const float*)d_in[10]; const float* br1 = (const float*)d_in[11];
  const float* Wu2  = (const float*)d_in[8];  const float* bu2 = (const float*)d_in[9];
  const float* Wr2  = (const float*)d_in[12]; const float* br2 = (const float*)d_in[13];
  const float* Wn1  = (const float*)d_in[14]; const float* bn1 = (const float*)d_in[15];
  const float* Wn2  = (const float*)d_in[16]; const float* bn2 = (const float*)d_in[17];

  prep_weights<<<NFRAGS, 64, 0, stream>>>(Wo1, Wo2, Wu1, Wu2, Wr1, Wr2, Wn1, Wn2,
                                          (f16x8*)d_ws);
  vae_main<<<NTRAJ/16, 512, 0, stream>>>(data, ts, bo1, bo2, bu1, bu2, br1, br2,
                                         bn1, bn2, (const f16x8*)d_ws, (float*)d_out);
}

// Round 3
// 3807.663 us; speedup vs baseline: 1.1295x; 1.1295x over previous
//
#include <hip/hip_runtime.h>

typedef _Float16 f16x8 __attribute__((ext_vector_type(8)));
typedef _Float16 f16x4 __attribute__((ext_vector_type(4)));
typedef _Float16 f16x2 __attribute__((ext_vector_type(2)));
typedef float    f32x4 __attribute__((ext_vector_type(4)));
typedef float    f32x2 __attribute__((ext_vector_type(2)));

#define NTRAJ  4096
#define LSTEPS 128
#define IDIM   32
#define LD     64
#define NU     256

// frag bases (units of 1KB frags) in d_ws; lo-set lives at +NFRAGS
#define FB_WO1 0
#define FB_WO2 32
#define FB_WU1 64
#define FB_WU2 144
#define FB_WR1 176
#define FB_WR2 256
#define FB_WN1 288
#define FB_WN2 368
#define NFRAGS 432

// LDS pitches (elements)
#define PF  68    // fp32 width-64 arrays
#define PBY 72    // f16 width-64 arrays
#define PBX 40    // f16 width-32
#define PBH 520   // f16 width-512

static __device__ __forceinline__ float sigmoid_fast(float x) {
  float t = __builtin_amdgcn_exp2f(x * -1.442695041f);
  return __builtin_amdgcn_rcpf(1.0f + t);
}
static __device__ __forceinline__ float tanh_fast(float x) {
  float t = __builtin_amdgcn_exp2f(x * -2.885390082f);
  return __builtin_amdgcn_rcpf(1.0f + t) * 2.0f - 1.0f;
}
static __device__ __forceinline__ f16x2 split2(float v) {
  _Float16 h = (_Float16)v;
  f16x2 r; r[0] = h; r[1] = (_Float16)(v - (float)h);
  return r;
}

// triple-product split-fp16 MFMA: weights as A, activations as B
static __device__ __forceinline__ f32x4 mm3(f16x8 ah, f16x8 al, f16x8 bh, f16x8 bl, f32x4 c) {
  c = __builtin_amdgcn_mfma_f32_16x16x32_f16(ah, bh, c, 0, 0, 0);
  c = __builtin_amdgcn_mfma_f32_16x16x32_f16(al, bh, c, 0, 0, 0);
  c = __builtin_amdgcn_mfma_f32_16x16x32_f16(ah, bl, c, 0, 0, 0);
  return c;
}

// ---------------- weight prep: fp32 [K][N] -> f16 hi/lo A-fragment swizzle ----------------
// frag (kc, mt): lane l holds W[kc*32 + (l>>4)*8 + j][mt*16 + (l&15)]  == A[m=l&15][k=q8+j]
__global__ void prep_weights(const float* __restrict__ Wo1, const float* __restrict__ Wo2,
                             const float* __restrict__ Wu1, const float* __restrict__ Wu2,
                             const float* __restrict__ Wr1, const float* __restrict__ Wr2,
                             const float* __restrict__ Wn1, const float* __restrict__ Wn2,
                             f16x8* __restrict__ ws)
{
  int f = blockIdx.x;
  const float* W; int N; int base;
  if (f < 32)       { W = Wo1; N = 256; base = 0;   }
  else if (f < 64)  { W = Wo2; N = 64;  base = 32;  }
  else if (f < 144) { W = Wu1; N = 256; base = 64;  }
  else if (f < 176) { W = Wu2; N = 64;  base = 144; }
  else if (f < 256) { W = Wr1; N = 256; base = 176; }
  else if (f < 288) { W = Wr2; N = 64;  base = 256; }
  else if (f < 368) { W = Wn1; N = 256; base = 288; }
  else              { W = Wn2; N = 128; base = 368; }
  int fl  = f - base;
  int nts = N >> 4;
  int kc  = fl / nts;
  int nt  = fl - kc * nts;
  int l   = threadIdx.x;
  int k0  = kc * 32 + (l >> 4) * 8;
  int n   = nt * 16 + (l & 15);
  f16x8 h, lo;
#pragma unroll
  for (int j = 0; j < 8; ++j) {
    float w = W[(size_t)(k0 + j) * N + n];
    _Float16 hh = (_Float16)w;
    h[j]  = hh;
    lo[j] = (_Float16)(w - (float)hh);
  }
  ws[f * 64 + l]            = h;
  ws[(NFRAGS + f) * 64 + l] = lo;
}

// ---------------- main persistent-scan kernel ----------------
__global__ __launch_bounds__(1024, 4) void vae_main(
    const float* __restrict__ data, const float* __restrict__ ts,
    const float* __restrict__ bo1, const float* __restrict__ bo2,
    const float* __restrict__ bu1, const float* __restrict__ bu2,
    const float* __restrict__ br1, const float* __restrict__ br2,
    const float* __restrict__ bn1, const float* __restrict__ bn2,
    const f16x8* __restrict__ WF, float* __restrict__ out)
{
  __shared__ __align__(16) float s_y[16*PF], s_lv[16*PF], s_yode[16*PF], s_U[16*PF], s_R[16*PF];
  __shared__ __align__(16) float s_bias[1344];
  __shared__ float s_dts[LSTEPS];
  __shared__ __align__(16) _Float16 b_y[2][16*PBY], b_lv[2][16*PBY], b_yode[2][16*PBY];
  __shared__ __align__(16) _Float16 b_x[2][16*PBX], b_hid[2][16*PBH];

  const int tid  = threadIdx.x;
  const int lane = tid & 63;
  const int wave = tid >> 6;       // 0..15
  const int q    = lane >> 4;
  const int l16  = lane & 15;
  const int q8   = q * 8;
  const int traj0 = blockIdx.x * 16;

#define AH(base, nts, kc, mt) WF[((base) + (kc)*(nts) + (mt)) * 64 + lane]
#define AL(base, nts, kc, mt) WF[(NFRAGS + (base) + (kc)*(nts) + (mt)) * 64 + lane]
#define LDB(arr, pitch, koff) (*(const f16x8*)&(arr)[(l16)*(pitch) + (koff) + q8])

  // stage biases / dts, zero state
  for (int i = tid; i < NU; i += 1024) s_bias[0    + i] = bo1[i];
  if (tid < LD)                        s_bias[256  + tid] = bo2[tid];
  for (int i = tid; i < NU; i += 1024) s_bias[320  + i] = bu1[i];
  if (tid < LD)                        s_bias[576  + tid] = bu2[tid];
  for (int i = tid; i < NU; i += 1024) s_bias[640  + i] = br1[i];
  if (tid < LD)                        s_bias[896  + tid] = br2[tid];
  for (int i = tid; i < NU; i += 1024) s_bias[960  + i] = bn1[i];
  if (tid < 2*LD)                      s_bias[1216 + tid] = bn2[tid];
  if (tid < LSTEPS-1) s_dts[tid] = (tid == 0) ? (ts[1] - ts[0]) : (ts[tid] - ts[tid+1]);
  for (int i = tid; i < 16*PF;  i += 1024) { s_y[i] = 0.f; s_lv[i] = 0.f; }
  for (int i = tid; i < 2*16*PBY; i += 1024) {
    ((_Float16*)b_y)[i]  = (_Float16)0.f;
    ((_Float16*)b_lv)[i] = (_Float16)0.f;
  }
  __syncthreads();

  for (int t = 0; t < LSTEPS-1; ++t) {
    // ---- S1: hid_o = tanh(Wo1^T y^T + bo1)  [256 x 16traj], 16 waves x 1 mtile ----
    {
      f16x8 b0h = LDB(b_y[0], PBY, 0),  b0l = LDB(b_y[1], PBY, 0);
      f16x8 b1h = LDB(b_y[0], PBY, 32), b1l = LDB(b_y[1], PBY, 32);
      f32x4 acc = {0.f,0.f,0.f,0.f};
      acc = mm3(AH(FB_WO1,16,0,wave), AL(FB_WO1,16,0,wave), b0h, b0l, acc);
      acc = mm3(AH(FB_WO1,16,1,wave), AL(FB_WO1,16,1,wave), b1h, b1l, acc);
      int f0 = wave*16 + q*4;
      f32x4 bb = *(const f32x4*)&s_bias[0 + f0];
      f16x4 hv, lv4;
#pragma unroll
      for (int r = 0; r < 4; ++r) {
        f16x2 sp = split2(tanh_fast(acc[r] + bb[r]));
        hv[r] = sp[0]; lv4[r] = sp[1];
      }
      *(f16x4*)&b_hid[0][l16*PBH + f0] = hv;
      *(f16x4*)&b_hid[1][l16*PBH + f0] = lv4;
    }
    __syncthreads();

    // ---- S2: yode = y + dt*(Wo2^T hid_o + bo2) [64x16], waves 0-3; waves 12-15 stage x(t) ----
    if (wave < 4) {
      float dt = s_dts[t];
      f32x4 acc = {0.f,0.f,0.f,0.f};
#pragma unroll
      for (int kc = 0; kc < 8; ++kc)
        acc = mm3(AH(FB_WO2,4,kc,wave), AL(FB_WO2,4,kc,wave),
                  LDB(b_hid[0], PBH, kc*32), LDB(b_hid[1], PBH, kc*32), acc);
      int f0 = wave*16 + q*4;
      f32x4 bb = *(const f32x4*)&s_bias[256 + f0];
      f32x4 yv = *(const f32x4*)&s_y[l16*PF + f0];
      f32x4 yo;
      f16x4 hv, lv4;
#pragma unroll
      for (int r = 0; r < 4; ++r) {
        yo[r] = yv[r] + dt * (acc[r] + bb[r]);
        f16x2 sp = split2(yo[r]);
        hv[r] = sp[0]; lv4[r] = sp[1];
      }
      *(f32x4*)&s_yode[l16*PF + f0] = yo;
      *(f16x4*)&b_yode[0][l16*PBY + f0] = hv;
      *(f16x4*)&b_yode[1][l16*PBY + f0] = lv4;
    } else if (wave >= 12) {
      int idx = tid - 768;                 // 0..255
      int row = idx >> 4, c0 = (idx & 15) * 2;
      f32x2 d = *(const f32x2*)&data[(size_t)(traj0 + row) * LSTEPS * IDIM
                                     + (size_t)(t+1) * IDIM + c0];
      f16x2 xh, xl;
      f16x2 s0 = split2(d[0]), s1 = split2(d[1]);
      xh[0] = s0[0]; xl[0] = s0[1];
      xh[1] = s1[0]; xl[1] = s1[1];
      *(f16x2*)&b_x[0][row*PBX + c0] = xh;
      *(f16x2*)&b_x[1][row*PBX + c0] = xl;
    }
    __syncthreads();

    // ---- S3: hid_ur = tanh([Wu1|Wr1]^T yc + b)  [512x16], 16 waves x 2 mtiles ----
    {
      f16x8 bh[5], bl[5];
      bh[0] = LDB(b_yode[0], PBY, 0);  bl[0] = LDB(b_yode[1], PBY, 0);
      bh[1] = LDB(b_yode[0], PBY, 32); bl[1] = LDB(b_yode[1], PBY, 32);
      bh[2] = LDB(b_lv[0],   PBY, 0);  bl[2] = LDB(b_lv[1],   PBY, 0);
      bh[3] = LDB(b_lv[0],   PBY, 32); bl[3] = LDB(b_lv[1],   PBY, 32);
      bh[4] = LDB(b_x[0],    PBX, 0);  bl[4] = LDB(b_x[1],    PBX, 0);
      int mt0 = wave * 2;
      int isR = wave >> 3;
      int fb  = isR ? FB_WR1 : FB_WU1;
      f32x4 acc[2];
      acc[0] = (f32x4){0.f,0.f,0.f,0.f};
      acc[1] = (f32x4){0.f,0.f,0.f,0.f};
#pragma unroll
      for (int kc = 0; kc < 5; ++kc)
#pragma unroll
        for (int s = 0; s < 2; ++s) {
          int mt = (mt0 + s) & 15;
          acc[s] = mm3(AH(fb,16,kc,mt), AL(fb,16,kc,mt), bh[kc], bl[kc], acc[s]);
        }
#pragma unroll
      for (int s = 0; s < 2; ++s) {
        int col0 = (mt0 + s) * 16 + q*4;          // 0..511
        int bidx = isR ? (640 + col0 - 256) : (320 + col0);
        f32x4 bb = *(const f32x4*)&s_bias[bidx];
        f16x4 hv, lv4;
#pragma unroll
        for (int r = 0; r < 4; ++r) {
          f16x2 sp = split2(tanh_fast(acc[s][r] + bb[r]));
          hv[r] = sp[0]; lv4[r] = sp[1];
        }
        *(f16x4*)&b_hid[0][l16*PBH + col0] = hv;
        *(f16x4*)&b_hid[1][l16*PBH + col0] = lv4;
      }
    }
    __syncthreads();

    // ---- S4: U = sig(Wu2^T hid_u + bu2), R = sig(Wr2^T hid_r + br2), waves 0-7 ----
    if (wave < 8) {
      int isR  = wave >> 2;
      int mt   = wave & 3;
      int fb   = isR ? FB_WR2 : FB_WU2;
      int aofs = isR ? 256 : 0;
      f32x4 acc = {0.f,0.f,0.f,0.f};
#pragma unroll
      for (int kc = 0; kc < 8; ++kc)
        acc = mm3(AH(fb,4,kc,mt), AL(fb,4,kc,mt),
                  LDB(b_hid[0], PBH, aofs + kc*32), LDB(b_hid[1], PBH, aofs + kc*32), acc);
      int f0 = mt*16 + q*4;
      f32x4 bb = *(const f32x4*)&s_bias[(isR ? 896 : 576) + f0];
      float* dst = isR ? s_R : s_U;
      f32x4 o;
#pragma unroll
      for (int r = 0; r < 4; ++r) o[r] = sigmoid_fast(acc[r] + bb[r]);
      *(f32x4*)&dst[l16*PF + f0] = o;
    }
    __syncthreads();

    // ---- S5: hid_n = tanh(Wn1^T cc + bn1) [256x16]; cc built inline ----
    {
      f16x8 bh[5], bl[5];
#pragma unroll
      for (int kc = 0; kc < 4; ++kc) {
        int f0 = kc*32 + q8;                       // 0..127
        const float* src = (kc < 2) ? &s_yode[l16*PF + f0] : &s_lv[l16*PF + (f0 - 64)];
        const float* rr  = &s_R[l16*PF + (f0 & 63)];
        f32x4 v0 = *(const f32x4*)src, v1 = *(const f32x4*)(src + 4);
        f32x4 r0 = *(const f32x4*)rr,  r1 = *(const f32x4*)(rr + 4);
#pragma unroll
        for (int j = 0; j < 4; ++j) {
          f16x2 sa = split2(v0[j] * r0[j]);
          f16x2 sb = split2(v1[j] * r1[j]);
          bh[kc][j]   = sa[0]; bl[kc][j]   = sa[1];
          bh[kc][4+j] = sb[0]; bl[kc][4+j] = sb[1];
        }
      }
      bh[4] = LDB(b_x[0], PBX, 0);
      bl[4] = LDB(b_x[1], PBX, 0);
      f32x4 acc = {0.f,0.f,0.f,0.f};
#pragma unroll
      for (int kc = 0; kc < 5; ++kc)
        acc = mm3(AH(FB_WN1,16,kc,wave), AL(FB_WN1,16,kc,wave), bh[kc], bl[kc], acc);
      int f0 = wave*16 + q*4;
      f32x4 bb = *(const f32x4*)&s_bias[960 + f0];
      f16x4 hv, lv4;
#pragma unroll
      for (int r = 0; r < 4; ++r) {
        f16x2 sp = split2(tanh_fast(acc[r] + bb[r]));
        hv[r] = sp[0]; lv4[r] = sp[1];
      }
      *(f16x4*)&b_hid[0][l16*PBH + f0] = hv;
      *(f16x4*)&b_hid[1][l16*PBH + f0] = lv4;
    }
    __syncthreads();

    // ---- S6: h = Wn2^T hid_n + bn2 [128x16]; GRU gating + state update, waves 0-7 ----
    if (wave < 8) {
      f32x4 acc = {0.f,0.f,0.f,0.f};
#pragma unroll
      for (int kc = 0; kc < 8; ++kc)
        acc = mm3(AH(FB_WN2,8,kc,wave), AL(FB_WN2,8,kc,wave),
                  LDB(b_hid[0], PBH, kc*32), LDB(b_hid[1], PBH, kc*32), acc);
      int f0 = wave*16 + q*4;                      // 0..127
      f32x4 bb = *(const f32x4*)&s_bias[1216 + f0];
      if (wave < 4) {
        f32x4 u  = *(const f32x4*)&s_U[l16*PF + f0];
        f32x4 yo = *(const f32x4*)&s_yode[l16*PF + f0];
        f32x4 nv;
        f16x4 hv, lv4;
#pragma unroll
        for (int r = 0; r < 4; ++r) {
          float h = acc[r] + bb[r];
          nv[r] = (1.f - u[r]) * h + u[r] * yo[r];
          f16x2 sp = split2(nv[r]);
          hv[r] = sp[0]; lv4[r] = sp[1];
        }
        *(f32x4*)&s_y[l16*PF + f0] = nv;
        *(f16x4*)&b_y[0][l16*PBY + f0] = hv;
        *(f16x4*)&b_y[1][l16*PBY + f0] = lv4;
      } else {
        int f2 = f0 - 64;
        f32x4 u  = *(const f32x4*)&s_U[l16*PF + f2];
        f32x4 lv = *(const f32x4*)&s_lv[l16*PF + f2];
        f32x4 nl;
        f16x4 hv, lv4;
#pragma unroll
        for (int r = 0; r < 4; ++r) {
          float h = fabsf(acc[r] + bb[r]);
          nl[r] = (1.f - u[r]) * h + u[r] * lv[r];
          f16x2 sp = split2(nl[r]);
          hv[r] = sp[0]; lv4[r] = sp[1];
        }
        *(f32x4*)&s_lv[l16*PF + f2] = nl;
        *(f16x4*)&b_lv[0][l16*PBY + f2] = hv;
        *(f16x4*)&b_lv[1][l16*PBY + f2] = lv4;
      }
    }
    __syncthreads();
  }

  // write outputs: (yi, yi_logvar) concatenated — 1024 threads, 1 elem each per output
  {
    int row = tid >> 6, c = tid & 63;
    out[(size_t)(traj0 + row) * LD + c] = s_y[row*PF + c];
    out[(size_t)NTRAJ * LD + (size_t)(traj0 + row) * LD + c] = s_lv[row*PF + c];
  }
}

extern "C" void kernel_launch(void* const* d_in, const int* in_sizes, int n_in,
                              void* d_out, int out_size, void* d_ws, size_t ws_size,
                              hipStream_t stream) {
  const float* data = (const float*)d_in[0];
  const float* ts   = (const float*)d_in[1];
  const float* Wo1  = (const float*)d_in[2];  const float* bo1 = (const float*)d_in[3];
  const float* Wo2  = (const float*)d_in[4];  const float* bo2 = (const float*)d_in[5];
  const float* Wu1  = (const float*)d_in[6];  const float* bu1 = (const float*)d_in[7];
  const float* Wu2  = (const float*)d_in[8];  const float* bu2 = (const float*)d_in[9];
  const float* Wr1  = (const float*)d_in[10]; const float* br1 = (const float*)d_in[11];
  const float* Wr2  = (const float*)d_in[12]; const float* br2 = (const float*)d_in[13];
  const float* Wn1  = (const float*)d_in[14]; const float* bn1 = (const float*)d_in[15];
  const float* Wn2  = (const float*)d_in[16]; const float* bn2 = (const float*)d_in[17];

  prep_weights<<<NFRAGS, 64, 0, stream>>>(Wo1, Wo2, Wu1, Wu2, Wr1, Wr2, Wn1, Wn2,
                                          (f16x8*)d_ws);
  vae_main<<<NTRAJ/16, 1024, 0, stream>>>(data, ts, bo1, bo2, bu1, bu2, br1, br2,
                                          bn1, bn2, (const f16x8*)d_ws, (float*)d_out);
}